// Round 15
// baseline (390.951 us; speedup 1.0000x reference)
//
#include <hip/hip_runtime.h>
#include <hip/hip_fp16.h>

// Problem constants (reference: DIM=1024, 16 heads, hd=64, N=4096, B=1)
#define SEQ     4096
#define NHEADS  16
#define HDIM    64
#define DIMSZ   1024
#define ATT_SCALE 0.125f   // 64^-0.5

static constexpr size_t QSZ = (size_t)NHEADS * SEQ * HDIM;   // 4194304 elems

typedef __attribute__((ext_vector_type(8))) short short8;
typedef __attribute__((ext_vector_type(4))) short s16x4;
typedef __attribute__((ext_vector_type(8))) unsigned short ushort8;
typedef __attribute__((ext_vector_type(4))) float f32x4;
#define MFMA_F16(a, b, c) __builtin_amdgcn_mfma_f32_16x16x32_f16((a), (b), (c), 0, 0, 0)

__device__ __forceinline__ unsigned short f2hu(float x) {
    __half h = __float2half(x);   // RNE
    return *reinterpret_cast<unsigned short*>(&h);
}
__device__ __forceinline__ float hu2f(unsigned short u) {
    __half h = *reinterpret_cast<__half*>(&u);
    return __half2float(h);
}
__device__ __forceinline__ void split8h(float4 f0, float4 f1, ushort8& h, ushort8& l) {
    const float v[8] = {f0.x, f0.y, f0.z, f0.w, f1.x, f1.y, f1.z, f1.w};
    #pragma unroll
    for (int i = 0; i < 8; ++i) {
        const unsigned short hi = f2hu(v[i]);
        h[i] = hi;
        l[i] = f2hu(v[i] - hu2f(hi));
    }
}

// async global->LDS, 16B per lane. LDS dest is wave-uniform base + lane*16.
typedef __attribute__((address_space(1))) const unsigned int g_u32;
typedef __attribute__((address_space(3))) unsigned int lds_u32;
__device__ __forceinline__ void async16(unsigned short* lds, const unsigned short* g) {
    __builtin_amdgcn_global_load_lds((g_u32*)g, (lds_u32*)lds, 16, 0, 0);
}

// ---------------------------------------------------------------------------
// prep_split: x -> fp16 hi+lo planes (optional); W_qkv, W_proj -> fp16 hi only.
// ---------------------------------------------------------------------------
__global__ void prep_split(const float* __restrict__ x, unsigned short* __restrict__ xh,
                           unsigned short* __restrict__ xl, int nx,
                           const float* __restrict__ w0, unsigned short* __restrict__ w0h,
                           int n0,
                           const float* __restrict__ w1, unsigned short* __restrict__ w1h,
                           int n1)
{
    const int stride = gridDim.x * blockDim.x;
    const int tid = blockIdx.x * blockDim.x + threadIdx.x;
    for (int i = tid; i < (nx >> 2); i += stride) {
        float4 v = ((const float4*)x)[i];
        ushort4 h, l;
        h.x = f2hu(v.x); l.x = f2hu(v.x - hu2f(h.x));
        h.y = f2hu(v.y); l.y = f2hu(v.y - hu2f(h.y));
        h.z = f2hu(v.z); l.z = f2hu(v.z - hu2f(h.z));
        h.w = f2hu(v.w); l.w = f2hu(v.w - hu2f(h.w));
        ((ushort4*)xh)[i] = h; ((ushort4*)xl)[i] = l;
    }
    for (int i = tid; i < (n0 >> 2); i += stride) {
        float4 v = ((const float4*)w0)[i];
        ushort4 h;
        h.x = f2hu(v.x); h.y = f2hu(v.y); h.z = f2hu(v.z); h.w = f2hu(v.w);
        ((ushort4*)w0h)[i] = h;
    }
    for (int i = tid; i < (n1 >> 2); i += stride) {
        float4 v = ((const float4*)w1)[i];
        ushort4 h;
        h.x = f2hu(v.x); h.y = f2hu(v.y); h.z = f2hu(v.z); h.w = f2hu(v.w);
        ((ushort4*)w1h)[i] = h;
    }
}

// ---------------------------------------------------------------------------
// QKV GEMM, 256x192 tile, ring-3 schedule, 4M x 2N wave mapping (R14).
// C = A*B^T, 2-term fp16: Ah*Bh + Al*Bh. A=x (hi/lo planes), B=W_qkv hi.
// Tile 256x192 -> grid 16x16 = 256 blocks = exactly 1/CU (full chip fill).
// R14 change: waves remapped 2Mx4N -> 4Mx2N (per-wave 64 rows x 96 cols).
// LDS-read budget was the 52%-MfmaUtil ceiling: old mapping 19 b128/tile/wave
// (228 cyc) vs 48 MFMA (240 cyc); new mapping 8 A + 6 B = 14 b128 (168 cyc)
// for the same 48 MFMA -> reuse 2.5 -> 3.4, LDS reads off the critical path.
// acc[4][6] = 96 regs (unchanged); bfr[6] held across phases (+12 VGPR).
// Staging/ring/vmcnt identical to R9: BK=32, ring of 3 48KB buffers, tile
// t+2's 6 gload_lds issue during tile t (ph0/ph1) into retired slot; ONE
// vmcnt(6)+barrier per K-tile (never 0 in loop). B staged as 256 rows
// (over-read of rows 192-255 lands in adjacent workspace; never consumed).
// LDS XOR swizzle both-sides (rule #21): phys 16B slot = k_slot ^ ((row>>1)&3).
// [R10/R11 lesson: 32x32 shape closed — conflict-free LDS reads and
//  coalesced global reads are structurally exclusive under gload_lds.]
// Epilogue = QKV split with per-nf part (16-col groups never straddle).
// ---------------------------------------------------------------------------
__global__ __launch_bounds__(512, 2)
void qkv_gemm_8ph(const unsigned short* __restrict__ AHg,
                  const unsigned short* __restrict__ ALg,
                  const unsigned short* __restrict__ BHg,
                  unsigned short* __restrict__ QH, unsigned short* __restrict__ QL,
                  unsigned short* __restrict__ KH, unsigned short* __restrict__ VT)
{
    constexpr int K3 = 3072;
    constexpr int NT = K3 / 32;           // 96 K-tiles
    __shared__ __align__(16) unsigned short ring[3 * 24576];  // 147456 B

    const int t  = threadIdx.x;
    const int wv = t >> 6;
    const int ln = t & 63;
    const int lx = ln & 15;
    const int q4 = ln >> 4;
    const int wr = wv >> 1;               // 0..3  (M quarter, 64 rows)
    const int wc = wv & 1;                // 0..1  (N half, 96 cols)

    // XCD-aware bijective swizzle: 256 blocks, 256 % 8 == 0.
    const int bid = blockIdx.x;
    const int swz = (bid & 7) * 32 + (bid >> 3);
    const int m0 = (swz >> 4) * 256;      // 16 M-tiles
    const int n0 = (swz & 15) * 192;      // 16 N-tiles

    // staging geometry: each async16 line covers 128 rows x 32 k (8KB);
    // lane t -> row (t>>2), phys slot (t&3); logical k-block pre-swizzled.
    const int srow = t >> 2;
    const int sg8  = (((t & 3) ^ ((t >> 3) & 3)) << 3);   // global k elem off

    auto stage3a = [&](int tt, int b) {   // AH chunk0+1, AL chunk0
        const int kk = tt << 5;
        unsigned short* Lb = &ring[b * 24576 + wv * 512];
        const size_t ga = (size_t)(m0 + srow) * K3 + kk + sg8;
        async16(Lb,               AHg + ga);
        async16(Lb + 4096,        AHg + ga + (size_t)128 * K3);
        async16(Lb + 8192,        ALg + ga);
    };
    auto stage3b = [&](int tt, int b) {   // AL chunk1, B chunk0+1
        const int kk = tt << 5;
        unsigned short* Lb = &ring[b * 24576 + wv * 512];
        const size_t ga = (size_t)(m0 + srow) * K3 + kk + sg8;
        const size_t gb = (size_t)(n0 + srow) * K3 + kk + sg8;
        async16(Lb + 12288,       ALg + ga + (size_t)128 * K3);
        async16(Lb + 16384,       BHg + gb);
        async16(Lb + 20480,       BHg + gb + (size_t)128 * K3);
    };

    f32x4 acc[4][6];
    #pragma unroll
    for (int mf = 0; mf < 4; ++mf)
        #pragma unroll
        for (int nf = 0; nf < 6; ++nf)
            acc[mf][nf] = (f32x4){0.f, 0.f, 0.f, 0.f};

    // prologue: tiles 0,1 in flight (12 loads); wait tile 0 (6 newest remain)
    stage3a(0, 0); stage3b(0, 0);
    stage3a(1, 1); stage3b(1, 1);
    asm volatile("s_waitcnt vmcnt(6)" ::: "memory");
    __builtin_amdgcn_s_barrier();

    // swizzled per-lane read offset: 16B slot = q4 ^ ((lx>>1)&3)
    const int aswz8 = ((q4 ^ ((lx >> 1) & 3)) << 3);
    const int arow0 = (wr * 64 + lx) * 32 + aswz8;
    const int brow0 = (wc * 96 + lx) * 32 + aswz8;

    int c = 0;
    for (int kt = 0; kt < NT; ++kt) {
        const unsigned short* AHp = &ring[c * 24576];
        const unsigned short* ALp = AHp + 8192;
        const unsigned short* Bp  = AHp + 16384;
        int c2 = c + 2; if (c2 >= 3) c2 -= 3;   // == buffer of tile kt-1 (retired)
        const bool pf = (kt + 2 < NT);

        short8 bfr[6];
        #pragma unroll
        for (int ph = 0; ph < 4; ++ph) {        // phase = one mf (16 rows)
            if (ph == 0) {
                #pragma unroll
                for (int nf = 0; nf < 6; ++nf)
                    bfr[nf] = *(const short8*)&Bp[brow0 + nf * 512];
            }
            const int mo = arow0 + ph * 512;
            const short8 ahf = *(const short8*)&AHp[mo];
            const short8 alf = *(const short8*)&ALp[mo];
            if (ph == 0 && pf) stage3a(kt + 2, c2);
            if (ph == 1 && pf) stage3b(kt + 2, c2);
            __builtin_amdgcn_s_setprio(1);
            #pragma unroll
            for (int nf = 0; nf < 6; ++nf) {
                acc[ph][nf] = MFMA_F16(ahf, bfr[nf], acc[ph][nf]);
                acc[ph][nf] = MFMA_F16(alf, bfr[nf], acc[ph][nf]);
            }
            __builtin_amdgcn_s_setprio(0);
            if (ph == 3) {
                // tile boundary: ensure tile kt+1 arrived (6 newest = kt+2's)
                if (pf) asm volatile("s_waitcnt vmcnt(6)" ::: "memory");
                else    asm volatile("s_waitcnt vmcnt(0)" ::: "memory");
                __builtin_amdgcn_s_barrier();   // the ONLY barrier per K-tile
            }
        }
        ++c; if (c == 3) c = 0;
    }

    // ---- epilogue: QKV split (C-frag: row=q4*4+r, col=lx per 16x16) ----
    #pragma unroll
    for (int nf = 0; nf < 6; ++nf) {
        const int colb = n0 + wc * 96 + nf * 16;
        const int part = colb >> 10;             // per-nf: tile may straddle
        const int head = (colb >> 6) & 15;
        const int d0   = (colb & 63) + lx;
        if (part == 0) {
            #pragma unroll
            for (int mf = 0; mf < 4; ++mf) {
                const int row0 = m0 + wr * 64 + mf * 16 + q4 * 4;
                #pragma unroll
                for (int r = 0; r < 4; ++r) {
                    const float v = acc[mf][nf][r] * ATT_SCALE;
                    const unsigned short h = f2hu(v);
                    const size_t idx = ((size_t)head * SEQ + row0 + r) * HDIM + d0;
                    QH[idx] = h;
                    QL[idx] = f2hu(v - hu2f(h));
                }
            }
        } else if (part == 1) {
            #pragma unroll
            for (int mf = 0; mf < 4; ++mf) {
                const int row0 = m0 + wr * 64 + mf * 16 + q4 * 4;
                #pragma unroll
                for (int r = 0; r < 4; ++r) {
                    const size_t idx = ((size_t)head * SEQ + row0 + r) * HDIM + d0;
                    KH[idx] = f2hu(acc[mf][nf][r]);
                }
            }
        } else {
            unsigned short* base = VT + ((size_t)head * HDIM + d0) * SEQ;
            #pragma unroll
            for (int mf = 0; mf < 4; ++mf) {
                const int row0 = m0 + wr * 64 + mf * 16 + q4 * 4;
                ushort4 o;
                o.x = f2hu(acc[mf][nf][0]); o.y = f2hu(acc[mf][nf][1]);
                o.z = f2hu(acc[mf][nf][2]); o.w = f2hu(acc[mf][nf][3]);
                *(ushort4*)(base + row0) = o;
            }
        }
    }
}

// ---------------------------------------------------------------------------
// PROJ GEMM (R13): out = attn @ Wproj^T + bias, 2-term fp16, ring-3 schedule.
// 128x128 tiles: grid 256 blocks = 1/CU; 512 thr = 8 waves (2M x 4N).
// BK=32; ring-3 of 24KB = 72KB LDS; 3 async16/tile; boundary vmcnt(3);
// ONE barrier per K-tile. Same both-sides swizzle as qkv.
// ---------------------------------------------------------------------------
__global__ __launch_bounds__(512, 2)
void proj_gemm_r3(const unsigned short* __restrict__ AHg,
                  const unsigned short* __restrict__ ALg,
                  const unsigned short* __restrict__ BHg,
                  const float* __restrict__ bias, float* __restrict__ C)
{
    constexpr int K1 = 1024;
    constexpr int NT = K1 / 32;           // 32 K-tiles
    __shared__ __align__(16) unsigned short ring[3 * 12288];  // 73728 B

    const int t  = threadIdx.x;
    const int wv = t >> 6;
    const int ln = t & 63;
    const int lx = ln & 15;
    const int q4 = ln >> 4;
    const int wr = wv >> 2;               // 0..1  (M half, 64 rows)
    const int wc = wv & 3;                // 0..3  (N quarter, 32 cols)

    // XCD-aware bijective swizzle: 256 blocks = 8 x 32.
    const int bid = blockIdx.x;
    const int swz = (bid & 7) * 32 + (bid >> 3);
    const int m0 = (swz >> 3) * 128;      // 32 M-tiles
    const int n0 = (swz & 7) * 128;       // 8 N-tiles

    const int srow = t >> 2;
    const int sg8  = (((t & 3) ^ ((t >> 3) & 3)) << 3);

    auto stage2a = [&](int tt, int b) {   // AH, AL
        const int kk = tt << 5;
        unsigned short* Lb = &ring[b * 12288 + wv * 512];
        const size_t ga = (size_t)(m0 + srow) * K1 + kk + sg8;
        async16(Lb,               AHg + ga);
        async16(Lb + 4096,        ALg + ga);
    };
    auto stage1b = [&](int tt, int b) {   // B
        const int kk = tt << 5;
        unsigned short* Lb = &ring[b * 12288 + wv * 512];
        const size_t gb = (size_t)(n0 + srow) * K1 + kk + sg8;
        async16(Lb + 8192,        BHg + gb);
    };

    f32x4 acc[4][2];
    #pragma unroll
    for (int mf = 0; mf < 4; ++mf)
        #pragma unroll
        for (int nf = 0; nf < 2; ++nf)
            acc[mf][nf] = (f32x4){0.f, 0.f, 0.f, 0.f};

    // prologue: tiles 0,1 in flight (6 loads); wait tile 0 (3 newest remain)
    stage2a(0, 0); stage1b(0, 0);
    stage2a(1, 1); stage1b(1, 1);
    asm volatile("s_waitcnt vmcnt(3)" ::: "memory");
    __builtin_amdgcn_s_barrier();

    const int aswz8 = ((q4 ^ ((lx >> 1) & 3)) << 3);
    const int arow0 = (wr * 64 + lx) * 32 + aswz8;
    const int brow0 = (wc * 32 + lx) * 32 + aswz8;

    int c = 0;
    for (int kt = 0; kt < NT; ++kt) {
        const unsigned short* AHp = &ring[c * 12288];
        const unsigned short* ALp = AHp + 4096;
        const unsigned short* Bp  = AHp + 8192;
        int c2 = c + 2; if (c2 >= 3) c2 -= 3;   // retired slot
        const bool pf = (kt + 2 < NT);

        short8 bfr[2];
        #pragma unroll
        for (int ph = 0; ph < 4; ++ph) {        // phase = one mf (16 rows)
            if (ph == 0) {
                #pragma unroll
                for (int nf = 0; nf < 2; ++nf)
                    bfr[nf] = *(const short8*)&Bp[brow0 + nf * 512];
            }
            const int mo = arow0 + ph * 512;
            const short8 ahf = *(const short8*)&AHp[mo];
            const short8 alf = *(const short8*)&ALp[mo];
            if (ph == 0 && pf) stage2a(kt + 2, c2);
            if (ph == 1 && pf) stage1b(kt + 2, c2);
            __builtin_amdgcn_s_setprio(1);
            #pragma unroll
            for (int nf = 0; nf < 2; ++nf) {
                acc[ph][nf] = MFMA_F16(ahf, bfr[nf], acc[ph][nf]);
                acc[ph][nf] = MFMA_F16(alf, bfr[nf], acc[ph][nf]);
            }
            __builtin_amdgcn_s_setprio(0);
            if (ph == 3) {
                if (pf) asm volatile("s_waitcnt vmcnt(3)" ::: "memory");
                else    asm volatile("s_waitcnt vmcnt(0)" ::: "memory");
                __builtin_amdgcn_s_barrier();   // the ONLY barrier per K-tile
            }
        }
        ++c; if (c == 3) c = 0;
    }

    // ---- epilogue: C = acc + bias (C-frag: row=q4*4+r, col=lx per 16x16) ----
    #pragma unroll
    for (int nf = 0; nf < 2; ++nf) {
        const int col = n0 + wc * 32 + nf * 16 + lx;
        const float bv = bias[col];
        #pragma unroll
        for (int mf = 0; mf < 4; ++mf) {
            const int row0 = m0 + wr * 64 + mf * 16 + q4 * 4;
            #pragma unroll
            for (int r = 0; r < 4; ++r)
                C[(size_t)(row0 + r) * DIMSZ + col] = acc[mf][nf][r] + bv;
        }
    }
}

// ---------------------------------------------------------------------------
// MFMA GEMM (fallback path only, !xsplit): C = A*B^T, fp16 2-term, MODE 1
// QKV epilogue. 128x128 tile, BK=32, 256 thr = 4 waves, reg-staged split.
// ---------------------------------------------------------------------------
template <int MODE, bool ASPLIT>
__global__ __launch_bounds__(256, 3)
void mfma_gemm_abt(const float* __restrict__ A,
                   const unsigned short* __restrict__ AHg,
                   const unsigned short* __restrict__ ALg,
                   const unsigned short* __restrict__ BHg,
                   const float* __restrict__ bias, float* __restrict__ C,
                   unsigned short* __restrict__ QH, unsigned short* __restrict__ QL,
                   unsigned short* __restrict__ KH, unsigned short* __restrict__ VT,
                   int M, int N, int K)
{
    constexpr int LDP = ASPLIT ? 32 : 40;   // LDS row stride (ushorts)
    __shared__ unsigned short AHs[128 * LDP];
    __shared__ unsigned short ALs[128 * LDP];
    __shared__ unsigned short BHs[128 * LDP];

    const int t  = threadIdx.x;
    const int wv = t >> 6;
    const int ln = t & 63;
    const int lx = ln & 15;
    const int q4 = ln >> 4;
    const int m0 = blockIdx.y * 128;
    const int n0 = blockIdx.x * 128;

    f32x4 acc[2][8];
    #pragma unroll
    for (int mf = 0; mf < 2; ++mf)
        #pragma unroll
        for (int nf = 0; nf < 8; ++nf)
            acc[mf][nf] = (f32x4){0.f, 0.f, 0.f, 0.f};

    for (int k0 = 0; k0 < K; k0 += 32) {
        if constexpr (ASPLIT) {
            const int rowc = ln >> 2;            // row within chunk
            const int c8   = (ln & 3) << 3;      // ushort offset within row
            #pragma unroll
            for (int rep = 0; rep < 2; ++rep) {
                const int chunk = rep * 4 + wv;  // 0..7, wave-uniform
                const int r = chunk * 16 + rowc;
                const size_t goff = (size_t)(m0 + r) * K + k0 + c8;
                const size_t boff = (size_t)(n0 + r) * K + k0 + c8;
                async16(&AHs[chunk * 16 * LDP], AHg + goff);
                async16(&ALs[chunk * 16 * LDP], ALg + goff);
                async16(&BHs[chunk * 16 * LDP], BHg + boff);
            }
        } else {
            #pragma unroll
            for (int rep = 0; rep < 2; ++rep) {
                const int task = rep * 256 + t;          // 0..511
                const int r  = task >> 2;
                const int sg = (task & 3) << 3;          // element offset 0,8,16,24
                {
                    const float* p = A + (size_t)(m0 + r) * K + k0 + sg;
                    float4 f0 = *(const float4*)p;
                    float4 f1 = *(const float4*)(p + 4);
                    ushort8 h, l; split8h(f0, f1, h, l);
                    *(ushort8*)&AHs[r * LDP + sg] = h;
                    *(ushort8*)&ALs[r * LDP + sg] = l;
                }
                {
                    const size_t off = (size_t)(n0 + r) * K + k0 + sg;
                    *(ushort8*)&BHs[r * LDP + sg] = *(const ushort8*)(BHg + off);
                }
            }
        }
        __syncthreads();   // drains vmcnt (global_load_lds) + lgkmcnt

        short8 ah[2], al[2];
        #pragma unroll
        for (int mf = 0; mf < 2; ++mf) {
            const int row = wv * 32 + mf * 16 + lx;
            ah[mf] = *(const short8*)&AHs[row * LDP + q4 * 8];
            al[mf] = *(const short8*)&ALs[row * LDP + q4 * 8];
        }
        #pragma unroll
        for (int nf = 0; nf < 8; ++nf) {
            const short8 bh = *(const short8*)&BHs[(nf * 16 + lx) * LDP + q4 * 8];
            #pragma unroll
            for (int mf = 0; mf < 2; ++mf) {
                acc[mf][nf] = MFMA_F16(ah[mf], bh, acc[mf][nf]);
                acc[mf][nf] = MFMA_F16(al[mf], bh, acc[mf][nf]);
            }
        }
        __syncthreads();
    }

    // ---- epilogue (C-frag: row = q4*4+r, col = lx within each 16x16) ----
    if constexpr (MODE == 0) {
        #pragma unroll
        for (int nf = 0; nf < 8; ++nf) {
            const int col = n0 + nf * 16 + lx;
            const float bv = bias[col];
            #pragma unroll
            for (int mf = 0; mf < 2; ++mf) {
                const int row0 = m0 + wv * 32 + mf * 16 + q4 * 4;
                #pragma unroll
                for (int r = 0; r < 4; ++r)
                    C[(size_t)(row0 + r) * N + col] = acc[mf][nf][r] + bv;
            }
        }
    } else {
        const int part = n0 >> 10;                   // whole block in one part
        #pragma unroll
        for (int nf = 0; nf < 8; ++nf) {
            const int colb = n0 + nf * 16;
            const int head = (colb >> 6) & 15;
            const int d0   = (colb & 63) + lx;
            if (part == 0) {
                #pragma unroll
                for (int mf = 0; mf < 2; ++mf) {
                    const int row0 = m0 + wv * 32 + mf * 16 + q4 * 4;
                    #pragma unroll
                    for (int r = 0; r < 4; ++r) {
                        const float v = acc[mf][nf][r] * ATT_SCALE;
                        const unsigned short h = f2hu(v);
                        const size_t idx = ((size_t)head * SEQ + row0 + r) * HDIM + d0;
                        QH[idx] = h;
                        QL[idx] = f2hu(v - hu2f(h));
                    }
                }
            } else if (part == 1) {
                #pragma unroll
                for (int mf = 0; mf < 2; ++mf) {
                    const int row0 = m0 + wv * 32 + mf * 16 + q4 * 4;
                    #pragma unroll
                    for (int r = 0; r < 4; ++r) {
                        const size_t idx = ((size_t)head * SEQ + row0 + r) * HDIM + d0;
                        KH[idx] = f2hu(acc[mf][nf][r]);
                    }
                }
            } else {
                unsigned short* base = VT + ((size_t)head * HDIM + d0) * SEQ;
                #pragma unroll
                for (int mf = 0; mf < 2; ++mf) {
                    const int row0 = m0 + wv * 32 + mf * 16 + q4 * 4;
                    ushort4 o;
                    o.x = f2hu(acc[mf][nf][0]); o.y = f2hu(acc[mf][nf][1]);
                    o.z = f2hu(acc[mf][nf][2]); o.w = f2hu(acc[mf][nf][3]);
                    *(ushort4*)(base + row0) = o;
                }
            }
        }
    }
}

// ---------------------------------------------------------------------------
// Flash attention, fp16 MFMA, S^T formulation, register-resident P transit.
// R2 compute structure (Q hi/lo in registers, 4 waves, 64-query blocks) with
// global_load_lds DIRECT K/V staging into a double buffer (R6-proven).
// [R12 lesson: XCD-locality head-pinning swizzle reverted — all Q/K/V is
//  L3-resident, so the swizzle has no BW to save and cost ~2% (m160 regime).]
// LDS layout linear per rule #21 (both-sides XOR swizzle):
//   K [128][64]: stage lane writes global col8 (slot^(row&7)) into phys slot;
//     read kfh at phys slot (s*4+q4)^(kr&7)  -> 2-way bank aliasing (free).
//   V [64][128]: stage global col16 (slot^(rv&7)) into phys slot;
//     read v0/v1 (b64) at phys 16B-slot slot^(vr&7) -> 2-way (free).
// Buffers: KA[0,16K) VA[16K,32K) KB[32K,48K) VB[48K,64K); epilogue obuf/lbuf
// overlay [0,35840). 65536 B total, 2 blocks/CU.
// ---------------------------------------------------------------------------
__global__ __launch_bounds__(256, 2)
void attn_mfma(const unsigned short* __restrict__ QHg,
               const unsigned short* __restrict__ QLg,
               const unsigned short* __restrict__ KHg,
               const unsigned short* __restrict__ VTg,
               unsigned short* __restrict__ AttnH,
               unsigned short* __restrict__ AttnL)
{
    __shared__ __align__(16) char shraw[65536];
    unsigned short* KA = (unsigned short*)shraw;                 // [128][64]
    unsigned short* VA = (unsigned short*)(shraw + 16384);       // [64][128]
    unsigned short* KB = (unsigned short*)(shraw + 32768);
    unsigned short* VB = (unsigned short*)(shraw + 49152);
    float* obuf = (float*)shraw;                                 // [4][32][68]
    float* lbuf = (float*)(shraw + 34816);                       // [4][64]

    const int t  = threadIdx.x;
    const int wv = t >> 6;
    const int ln = t & 63;
    const int q4 = ln >> 4;
    const int lx = ln & 15;
    const int qb   = blockIdx.x;
    const int head = blockIdx.y;

    const unsigned short* Kh = KHg + (size_t)head * SEQ * HDIM;   // [n][64]
    const unsigned short* Vg = VTg + (size_t)head * HDIM * SEQ;   // [d][4096]

    // ---- Q B-frags, held in registers for the whole kernel ----
    short8 qh[4][2], ql[4][2];
    #pragma unroll
    for (int qt = 0; qt < 4; ++qt)
        #pragma unroll
        for (int s = 0; s < 2; ++s) {
            const size_t off = ((size_t)head * SEQ + (size_t)qb * 64 + qt * 16 + lx) * HDIM
                             + s * 32 + q4 * 8;
            qh[qt][s] = *(const short8*)(QHg + off);
            ql[qt][s] = *(const short8*)(QLg + off);
        }

    f32x4 o_acc[4][4];   // [dt][qt]: O^T[d=dt*16+q4*4+r][q=qt*16+lx] (wave-partial)
    float l_part[4] = {0.f, 0.f, 0.f, 0.f};
    #pragma unroll
    for (int dt = 0; dt < 4; ++dt)
        #pragma unroll
        for (int qt = 0; qt < 4; ++qt)
            o_acc[dt][qt] = (f32x4){0.f, 0.f, 0.f, 0.f};

    // per-thread staging constants (pre-swizzled global sources, rule #21)
    const int rK8 = t >> 3;                       // K sub-row within 32-row chunk
    const int gck = ((t & 7) ^ (rK8 & 7)) << 3;   // K global elem offset (swz)
    const int rV4 = t >> 4;                       // V sub-row within 16-row chunk
    const int gcv = ((t & 15) ^ (rV4 & 7)) << 3;  // V global elem offset (swz)

    auto issue_tile = [&](int kbase, unsigned short* KX, unsigned short* VX) {
        #pragma unroll
        for (int c = 0; c < 4; ++c) {
            async16(KX + (c * 32 + wv * 8) * 64,
                    Kh + (size_t)(kbase + c * 32 + rK8) * HDIM + gck);
            async16(VX + (c * 16 + wv * 4) * 128,
                    Vg + (size_t)(c * 16 + rV4) * SEQ + kbase + gcv);
        }
    };

    auto compute_tile = [&](const unsigned short* KX, const unsigned short* VX) {
        // ---- S^T = K Q^T per sub-tile; exp packs straight into PV B-frags ----
        short8 phi[4];
        #pragma unroll
        for (int st = 0; st < 2; ++st) {
            const int kr = st * 64 + wv * 16 + lx;   // this lane's A-row (key)
            short8 kfh[2];
            #pragma unroll
            for (int s = 0; s < 2; ++s)
                kfh[s] = *(const short8*)&KX[kr * 64 + (((s * 4 + q4) ^ (kr & 7)) << 3)];
            #pragma unroll
            for (int qt = 0; qt < 4; ++qt) {
                f32x4 sa = (f32x4){0.f, 0.f, 0.f, 0.f};
                __builtin_amdgcn_s_setprio(1);
                #pragma unroll
                for (int s = 0; s < 2; ++s) {
                    sa = MFMA_F16(kfh[s], qh[qt][s], sa);
                    sa = MFMA_F16(kfh[s], ql[qt][s], sa);
                }
                __builtin_amdgcn_s_setprio(0);
                #pragma unroll
                for (int r = 0; r < 4; ++r) {
                    const float e = __expf(sa[r]);
                    l_part[qt] += e;
                    phi[qt][st * 4 + r] = (short)f2hu(e);
                }
            }
        }
        // ---- O^T += V^T P^T (A=V^T two b64 reads w/ matching permutation) ----
        const int colb = wv * 32 + q4 * 8;     // byte col of v0 within V row
        const int sl0  = colb >> 4;            // logical 16B slot (0..7)
        const int sub  = (colb & 15) >> 1;     // elem offset within slot (0 or 4)
        #pragma unroll
        for (int dt = 0; dt < 4; ++dt) {
            const int vr = dt * 16 + lx;
            const s16x4 v0 = *(const s16x4*)&VX[vr * 128 + (((sl0    ) ^ (vr & 7)) << 3) + sub];
            const s16x4 v1 = *(const s16x4*)&VX[vr * 128 + (((sl0 + 8) ^ (vr & 7)) << 3) + sub];
            short8 vf;
            #pragma unroll
            for (int i = 0; i < 4; ++i) { vf[i] = v0[i]; vf[i + 4] = v1[i]; }
            __builtin_amdgcn_s_setprio(1);
            #pragma unroll
            for (int qt = 0; qt < 4; ++qt)
                o_acc[dt][qt] = MFMA_F16(vf, phi[qt], o_acc[dt][qt]);
            __builtin_amdgcn_s_setprio(0);
        }
    };

    // prologue: tile 0 -> buf A (syncthreads drains vmcnt)
    issue_tile(0, KA, VA);
    __syncthreads();

    // main loop: 32 tiles, pair-unrolled for static buffer selection.
    for (int i = 0; i < SEQ / 256; ++i) {
        const int mt = 2 * i;
        if (mt + 1 < SEQ / 128) issue_tile((mt + 1) * 128, KB, VB);
        compute_tile(KA, VA);
        __syncthreads();                       // drains B's DMA; closes A reads
        if (mt + 2 < SEQ / 128) issue_tile((mt + 2) * 128, KA, VA);
        compute_tile(KB, VB);
        __syncthreads();                       // drains A's DMA; closes B reads
    }

    // ---- epilogue: reduce l and O^T across the 4 waves, write split out ----
    float lw[4];
    #pragma unroll
    for (int qt = 0; qt < 4; ++qt) {
        float l = l_part[qt];
        l += __shfl_xor(l, 16);
        l += __shfl_xor(l, 32);
        lw[qt] = l;                                  // wave-total for q=qt*16+lx
    }
    if (q4 == 0) {
        #pragma unroll
        for (int qt = 0; qt < 4; ++qt)
            lbuf[wv * 64 + qt * 16 + lx] = lw[qt];
    }
    #pragma unroll
    for (int p = 0; p < 2; ++p) {
        #pragma unroll
        for (int dd = 0; dd < 2; ++dd) {
            const int dt = p * 2 + dd;
            #pragma unroll
            for (int qt = 0; qt < 4; ++qt)
                #pragma unroll
                for (int r = 0; r < 4; ++r)
                    obuf[wv * 2176 + (dd * 16 + q4 * 4 + r) * 68 + qt * 16 + lx]
                        = o_acc[dt][qt][r];
        }
        __syncthreads();
        {
            const int q  = t >> 2;
            const int dg = (t & 3) << 3;
            const float linv = 1.f / (lbuf[q] + lbuf[64 + q] + lbuf[128 + q] + lbuf[192 + q]);
            ushort8 ho, lo;
            #pragma unroll
            for (int j = 0; j < 8; ++j) {
                const int dloc = dg + j;
                const float s = obuf[dloc * 68 + q] + obuf[2176 + dloc * 68 + q]
                              + obuf[4352 + dloc * 68 + q] + obuf[6528 + dloc * 68 + q];
                const float v = s * linv;
                const unsigned short h = f2hu(v);
                ho[j] = (short)h;
                lo[j] = (short)f2hu(v - hu2f(h));
            }
            const size_t ob = (size_t)(qb * 64 + q) * DIMSZ + head * HDIM + p * 32 + dg;
            *(ushort8*)(AttnH + ob) = ho;
            *(ushort8*)(AttnL + ob) = lo;
        }
        __syncthreads();
    }
}

// ---------------------------------------------------------------------------
extern "C" void kernel_launch(void* const* d_in, const int* in_sizes, int n_in,
                              void* d_out, int out_size, void* d_ws,
                              size_t ws_size, hipStream_t stream)
{
    const float* x     = (const float*)d_in[0];   // [4096, 3072]
    const float* Wqkv  = (const float*)d_in[1];   // [3072, 3072]
    const float* Wproj = (const float*)d_in[2];   // [1024, 1024]
    const float* bproj = (const float*)d_in[3];   // [1024]
    float* out = (float*)d_out;

    const size_t NWQ = (size_t)3072 * 3072;       // 9437184
    const size_t NWP = (size_t)1024 * 1024;       // 1048576
    const size_t NX  = (size_t)4096 * 3072;       // 12582912

    unsigned short* ub = (unsigned short*)d_ws;
    unsigned short* AttnH = ub;                   // [4096][1024]
    unsigned short* AttnL = ub + QSZ;
    unsigned short* QHg = ub + 2 * QSZ;           // [16][4096][64]
    unsigned short* QLg = ub + 3 * QSZ;
    unsigned short* KHg = ub + 4 * QSZ;
    unsigned short* VTg = ub + 5 * QSZ;           // [16][64][4096]
    unsigned short* WQH = ub + 6 * QSZ;           // [3072][3072] hi
    unsigned short* WPH = WQH + NWQ;              // [1024][1024] hi
    unsigned short* XH  = WPH + NWP;              // [4096][3072] hi
    unsigned short* XL  = XH + NX;                // [4096][3072] lo
    const bool xsplit = ws_size >= 121634816ull;

    // 0) prep: split x (hi/lo) if room; cast W_qkv/W_proj to fp16 hi.
    prep_split<<<2048, 256, 0, stream>>>(
        xsplit ? x : nullptr, XH, XL, xsplit ? (int)NX : 0,
        Wqkv, WQH, (int)NWQ, Wproj, WPH, (int)NWP);

    // 1) qkv = x @ Wqkv^T (fp16 2-term) -> pre-converted attention operands
    if (xsplit) {
        qkv_gemm_8ph<<<256, 512, 0, stream>>>(
            XH, XL, WQH, QHg, QLg, KHg, VTg);
    } else {
        dim3 g1(3 * DIMSZ / 128, SEQ / 128);   // 24 x 32
        mfma_gemm_abt<1, false><<<g1, 256, 0, stream>>>(
            x, nullptr, nullptr, WQH, nullptr, nullptr,
            QHg, QLg, KHg, VTg, SEQ, 3 * DIMSZ, 3 * DIMSZ);
    }

    // 2) attention (S^T keys-per-wave, gload_lds dbuf staging)
    dim3 g2(SEQ / 64, NHEADS);             // 64 x 16
    attn_mfma<<<g2, 256, 0, stream>>>(QHg, QLg, KHg, VTg, AttnH, AttnL);

    // 3) out = attn @ Wproj^T + bproj (fp16 2-term, ring-3 schedule)
    proj_gemm_r3<<<256, 512, 0, stream>>>(AttnH, AttnL, WPH, bproj, out);
}

// Round 16
// 386.591 us; speedup vs baseline: 1.0113x; 1.0113x over previous
//
#include <hip/hip_runtime.h>
#include <hip/hip_fp16.h>

// Problem constants (reference: DIM=1024, 16 heads, hd=64, N=4096, B=1)
#define SEQ     4096
#define NHEADS  16
#define HDIM    64
#define DIMSZ   1024
#define ATT_SCALE 0.125f   // 64^-0.5

static constexpr size_t QSZ = (size_t)NHEADS * SEQ * HDIM;   // 4194304 elems

typedef __attribute__((ext_vector_type(8))) short short8;
typedef __attribute__((ext_vector_type(4))) short s16x4;
typedef __attribute__((ext_vector_type(8))) unsigned short ushort8;
typedef __attribute__((ext_vector_type(4))) float f32x4;
#define MFMA_F16(a, b, c) __builtin_amdgcn_mfma_f32_16x16x32_f16((a), (b), (c), 0, 0, 0)

__device__ __forceinline__ unsigned short f2hu(float x) {
    __half h = __float2half(x);   // RNE
    return *reinterpret_cast<unsigned short*>(&h);
}
__device__ __forceinline__ float hu2f(unsigned short u) {
    __half h = *reinterpret_cast<__half*>(&u);
    return __half2float(h);
}
__device__ __forceinline__ void split8h(float4 f0, float4 f1, ushort8& h, ushort8& l) {
    const float v[8] = {f0.x, f0.y, f0.z, f0.w, f1.x, f1.y, f1.z, f1.w};
    #pragma unroll
    for (int i = 0; i < 8; ++i) {
        const unsigned short hi = f2hu(v[i]);
        h[i] = hi;
        l[i] = f2hu(v[i] - hu2f(hi));
    }
}

// async global->LDS, 16B per lane. LDS dest is wave-uniform base + lane*16.
typedef __attribute__((address_space(1))) const unsigned int g_u32;
typedef __attribute__((address_space(3))) unsigned int lds_u32;
__device__ __forceinline__ void async16(unsigned short* lds, const unsigned short* g) {
    __builtin_amdgcn_global_load_lds((g_u32*)g, (lds_u32*)lds, 16, 0, 0);
}

// ---------------------------------------------------------------------------
// prep_split: x -> fp16 hi+lo planes (optional); W_qkv, W_proj -> fp16 hi only.
// ---------------------------------------------------------------------------
__global__ void prep_split(const float* __restrict__ x, unsigned short* __restrict__ xh,
                           unsigned short* __restrict__ xl, int nx,
                           const float* __restrict__ w0, unsigned short* __restrict__ w0h,
                           int n0,
                           const float* __restrict__ w1, unsigned short* __restrict__ w1h,
                           int n1)
{
    const int stride = gridDim.x * blockDim.x;
    const int tid = blockIdx.x * blockDim.x + threadIdx.x;
    for (int i = tid; i < (nx >> 2); i += stride) {
        float4 v = ((const float4*)x)[i];
        ushort4 h, l;
        h.x = f2hu(v.x); l.x = f2hu(v.x - hu2f(h.x));
        h.y = f2hu(v.y); l.y = f2hu(v.y - hu2f(h.y));
        h.z = f2hu(v.z); l.z = f2hu(v.z - hu2f(h.z));
        h.w = f2hu(v.w); l.w = f2hu(v.w - hu2f(h.w));
        ((ushort4*)xh)[i] = h; ((ushort4*)xl)[i] = l;
    }
    for (int i = tid; i < (n0 >> 2); i += stride) {
        float4 v = ((const float4*)w0)[i];
        ushort4 h;
        h.x = f2hu(v.x); h.y = f2hu(v.y); h.z = f2hu(v.z); h.w = f2hu(v.w);
        ((ushort4*)w0h)[i] = h;
    }
    for (int i = tid; i < (n1 >> 2); i += stride) {
        float4 v = ((const float4*)w1)[i];
        ushort4 h;
        h.x = f2hu(v.x); h.y = f2hu(v.y); h.z = f2hu(v.z); h.w = f2hu(v.w);
        ((ushort4*)w1h)[i] = h;
    }
}

// ---------------------------------------------------------------------------
// QKV GEMM, 256x192 tile, ring-3 schedule, 4M x 2N wave mapping (R14/R9).
// C = A*B^T, 2-term fp16: Ah*Bh + Al*Bh. A=x (hi/lo planes), B=W_qkv hi.
// Tile 256x192 -> grid 16x16 = 256 blocks = exactly 1/CU (full chip fill).
// BK=32, ring of 3 48KB buffers; tile t+2's 6 gload_lds issue during tile t
// (ph0/ph1) into the retired slot; ONE vmcnt(6)+barrier per K-tile.
// LDS XOR swizzle both-sides (rule #21): phys 16B slot = k_slot ^ ((row>>1)&3).
// [Ledger of closed branches: 32x32 shape (R10/R11: conflict-free LDS reads
//  and coalesced global reads structurally exclusive under gload_lds);
//  wave-mapping 2Mx4N vs 4Mx2N (R14: identical — LDS reads not critical).]
// Epilogue = QKV split with per-nf part (16-col groups never straddle).
// ---------------------------------------------------------------------------
__global__ __launch_bounds__(512, 2)
void qkv_gemm_8ph(const unsigned short* __restrict__ AHg,
                  const unsigned short* __restrict__ ALg,
                  const unsigned short* __restrict__ BHg,
                  unsigned short* __restrict__ QH, unsigned short* __restrict__ QL,
                  unsigned short* __restrict__ KH, unsigned short* __restrict__ VT)
{
    constexpr int K3 = 3072;
    constexpr int NT = K3 / 32;           // 96 K-tiles
    __shared__ __align__(16) unsigned short ring[3 * 24576];  // 147456 B

    const int t  = threadIdx.x;
    const int wv = t >> 6;
    const int ln = t & 63;
    const int lx = ln & 15;
    const int q4 = ln >> 4;
    const int wr = wv >> 1;               // 0..3  (M quarter, 64 rows)
    const int wc = wv & 1;                // 0..1  (N half, 96 cols)

    // XCD-aware bijective swizzle: 256 blocks, 256 % 8 == 0.
    const int bid = blockIdx.x;
    const int swz = (bid & 7) * 32 + (bid >> 3);
    const int m0 = (swz >> 4) * 256;      // 16 M-tiles
    const int n0 = (swz & 15) * 192;      // 16 N-tiles

    // staging geometry: each async16 line covers 128 rows x 32 k (8KB);
    // lane t -> row (t>>2), phys slot (t&3); logical k-block pre-swizzled.
    const int srow = t >> 2;
    const int sg8  = (((t & 3) ^ ((t >> 3) & 3)) << 3);   // global k elem off

    auto stage3a = [&](int tt, int b) {   // AH chunk0+1, AL chunk0
        const int kk = tt << 5;
        unsigned short* Lb = &ring[b * 24576 + wv * 512];
        const size_t ga = (size_t)(m0 + srow) * K3 + kk + sg8;
        async16(Lb,               AHg + ga);
        async16(Lb + 4096,        AHg + ga + (size_t)128 * K3);
        async16(Lb + 8192,        ALg + ga);
    };
    auto stage3b = [&](int tt, int b) {   // AL chunk1, B chunk0+1
        const int kk = tt << 5;
        unsigned short* Lb = &ring[b * 24576 + wv * 512];
        const size_t ga = (size_t)(m0 + srow) * K3 + kk + sg8;
        const size_t gb = (size_t)(n0 + srow) * K3 + kk + sg8;
        async16(Lb + 12288,       ALg + ga + (size_t)128 * K3);
        async16(Lb + 16384,       BHg + gb);
        async16(Lb + 20480,       BHg + gb + (size_t)128 * K3);
    };

    f32x4 acc[4][6];
    #pragma unroll
    for (int mf = 0; mf < 4; ++mf)
        #pragma unroll
        for (int nf = 0; nf < 6; ++nf)
            acc[mf][nf] = (f32x4){0.f, 0.f, 0.f, 0.f};

    // prologue: tiles 0,1 in flight (12 loads); wait tile 0 (6 newest remain)
    stage3a(0, 0); stage3b(0, 0);
    stage3a(1, 1); stage3b(1, 1);
    asm volatile("s_waitcnt vmcnt(6)" ::: "memory");
    __builtin_amdgcn_s_barrier();

    // swizzled per-lane read offset: 16B slot = q4 ^ ((lx>>1)&3)
    const int aswz8 = ((q4 ^ ((lx >> 1) & 3)) << 3);
    const int arow0 = (wr * 64 + lx) * 32 + aswz8;
    const int brow0 = (wc * 96 + lx) * 32 + aswz8;

    int c = 0;
    for (int kt = 0; kt < NT; ++kt) {
        const unsigned short* AHp = &ring[c * 24576];
        const unsigned short* ALp = AHp + 8192;
        const unsigned short* Bp  = AHp + 16384;
        int c2 = c + 2; if (c2 >= 3) c2 -= 3;   // == buffer of tile kt-1 (retired)
        const bool pf = (kt + 2 < NT);

        short8 bfr[6];
        #pragma unroll
        for (int ph = 0; ph < 4; ++ph) {        // phase = one mf (16 rows)
            if (ph == 0) {
                #pragma unroll
                for (int nf = 0; nf < 6; ++nf)
                    bfr[nf] = *(const short8*)&Bp[brow0 + nf * 512];
            }
            const int mo = arow0 + ph * 512;
            const short8 ahf = *(const short8*)&AHp[mo];
            const short8 alf = *(const short8*)&ALp[mo];
            if (ph == 0 && pf) stage3a(kt + 2, c2);
            if (ph == 1 && pf) stage3b(kt + 2, c2);
            __builtin_amdgcn_s_setprio(1);
            #pragma unroll
            for (int nf = 0; nf < 6; ++nf) {
                acc[ph][nf] = MFMA_F16(ahf, bfr[nf], acc[ph][nf]);
                acc[ph][nf] = MFMA_F16(alf, bfr[nf], acc[ph][nf]);
            }
            __builtin_amdgcn_s_setprio(0);
            if (ph == 3) {
                // tile boundary: ensure tile kt+1 arrived (6 newest = kt+2's)
                if (pf) asm volatile("s_waitcnt vmcnt(6)" ::: "memory");
                else    asm volatile("s_waitcnt vmcnt(0)" ::: "memory");
                __builtin_amdgcn_s_barrier();   // the ONLY barrier per K-tile
            }
        }
        ++c; if (c == 3) c = 0;
    }

    // ---- epilogue: QKV split (C-frag: row=q4*4+r, col=lx per 16x16) ----
    #pragma unroll
    for (int nf = 0; nf < 6; ++nf) {
        const int colb = n0 + wc * 96 + nf * 16;
        const int part = colb >> 10;             // per-nf: tile may straddle
        const int head = (colb >> 6) & 15;
        const int d0   = (colb & 63) + lx;
        if (part == 0) {
            #pragma unroll
            for (int mf = 0; mf < 4; ++mf) {
                const int row0 = m0 + wr * 64 + mf * 16 + q4 * 4;
                #pragma unroll
                for (int r = 0; r < 4; ++r) {
                    const float v = acc[mf][nf][r] * ATT_SCALE;
                    const unsigned short h = f2hu(v);
                    const size_t idx = ((size_t)head * SEQ + row0 + r) * HDIM + d0;
                    QH[idx] = h;
                    QL[idx] = f2hu(v - hu2f(h));
                }
            }
        } else if (part == 1) {
            #pragma unroll
            for (int mf = 0; mf < 4; ++mf) {
                const int row0 = m0 + wr * 64 + mf * 16 + q4 * 4;
                #pragma unroll
                for (int r = 0; r < 4; ++r) {
                    const size_t idx = ((size_t)head * SEQ + row0 + r) * HDIM + d0;
                    KH[idx] = f2hu(acc[mf][nf][r]);
                }
            }
        } else {
            unsigned short* base = VT + ((size_t)head * HDIM + d0) * SEQ;
            #pragma unroll
            for (int mf = 0; mf < 4; ++mf) {
                const int row0 = m0 + wr * 64 + mf * 16 + q4 * 4;
                ushort4 o;
                o.x = f2hu(acc[mf][nf][0]); o.y = f2hu(acc[mf][nf][1]);
                o.z = f2hu(acc[mf][nf][2]); o.w = f2hu(acc[mf][nf][3]);
                *(ushort4*)(base + row0) = o;
            }
        }
    }
}

// ---------------------------------------------------------------------------
// PROJ GEMM (R13): out = attn @ Wproj^T + bias, 2-term fp16, ring-3 schedule.
// 128x128 tiles: grid 256 blocks = 1/CU; 512 thr = 8 waves (2M x 4N).
// BK=32; ring-3 of 24KB = 72KB LDS; 3 async16/tile; boundary vmcnt(3);
// ONE barrier per K-tile. Same both-sides swizzle as qkv.
// ---------------------------------------------------------------------------
__global__ __launch_bounds__(512, 2)
void proj_gemm_r3(const unsigned short* __restrict__ AHg,
                  const unsigned short* __restrict__ ALg,
                  const unsigned short* __restrict__ BHg,
                  const float* __restrict__ bias, float* __restrict__ C)
{
    constexpr int K1 = 1024;
    constexpr int NT = K1 / 32;           // 32 K-tiles
    __shared__ __align__(16) unsigned short ring[3 * 12288];  // 73728 B

    const int t  = threadIdx.x;
    const int wv = t >> 6;
    const int ln = t & 63;
    const int lx = ln & 15;
    const int q4 = ln >> 4;
    const int wr = wv >> 2;               // 0..1  (M half, 64 rows)
    const int wc = wv & 3;                // 0..3  (N quarter, 32 cols)

    // XCD-aware bijective swizzle: 256 blocks = 8 x 32.
    const int bid = blockIdx.x;
    const int swz = (bid & 7) * 32 + (bid >> 3);
    const int m0 = (swz >> 3) * 128;      // 32 M-tiles
    const int n0 = (swz & 7) * 128;       // 8 N-tiles

    const int srow = t >> 2;
    const int sg8  = (((t & 3) ^ ((t >> 3) & 3)) << 3);

    auto stage2a = [&](int tt, int b) {   // AH, AL
        const int kk = tt << 5;
        unsigned short* Lb = &ring[b * 12288 + wv * 512];
        const size_t ga = (size_t)(m0 + srow) * K1 + kk + sg8;
        async16(Lb,               AHg + ga);
        async16(Lb + 4096,        ALg + ga);
    };
    auto stage1b = [&](int tt, int b) {   // B
        const int kk = tt << 5;
        unsigned short* Lb = &ring[b * 12288 + wv * 512];
        const size_t gb = (size_t)(n0 + srow) * K1 + kk + sg8;
        async16(Lb + 8192,        BHg + gb);
    };

    f32x4 acc[4][2];
    #pragma unroll
    for (int mf = 0; mf < 4; ++mf)
        #pragma unroll
        for (int nf = 0; nf < 2; ++nf)
            acc[mf][nf] = (f32x4){0.f, 0.f, 0.f, 0.f};

    // prologue: tiles 0,1 in flight (6 loads); wait tile 0 (3 newest remain)
    stage2a(0, 0); stage1b(0, 0);
    stage2a(1, 1); stage1b(1, 1);
    asm volatile("s_waitcnt vmcnt(3)" ::: "memory");
    __builtin_amdgcn_s_barrier();

    const int aswz8 = ((q4 ^ ((lx >> 1) & 3)) << 3);
    const int arow0 = (wr * 64 + lx) * 32 + aswz8;
    const int brow0 = (wc * 32 + lx) * 32 + aswz8;

    int c = 0;
    for (int kt = 0; kt < NT; ++kt) {
        const unsigned short* AHp = &ring[c * 12288];
        const unsigned short* ALp = AHp + 4096;
        const unsigned short* Bp  = AHp + 8192;
        int c2 = c + 2; if (c2 >= 3) c2 -= 3;   // retired slot
        const bool pf = (kt + 2 < NT);

        short8 bfr[2];
        #pragma unroll
        for (int ph = 0; ph < 4; ++ph) {        // phase = one mf (16 rows)
            if (ph == 0) {
                #pragma unroll
                for (int nf = 0; nf < 2; ++nf)
                    bfr[nf] = *(const short8*)&Bp[brow0 + nf * 512];
            }
            const int mo = arow0 + ph * 512;
            const short8 ahf = *(const short8*)&AHp[mo];
            const short8 alf = *(const short8*)&ALp[mo];
            if (ph == 0 && pf) stage2a(kt + 2, c2);
            if (ph == 1 && pf) stage1b(kt + 2, c2);
            __builtin_amdgcn_s_setprio(1);
            #pragma unroll
            for (int nf = 0; nf < 2; ++nf) {
                acc[ph][nf] = MFMA_F16(ahf, bfr[nf], acc[ph][nf]);
                acc[ph][nf] = MFMA_F16(alf, bfr[nf], acc[ph][nf]);
            }
            __builtin_amdgcn_s_setprio(0);
            if (ph == 3) {
                if (pf) asm volatile("s_waitcnt vmcnt(3)" ::: "memory");
                else    asm volatile("s_waitcnt vmcnt(0)" ::: "memory");
                __builtin_amdgcn_s_barrier();   // the ONLY barrier per K-tile
            }
        }
        ++c; if (c == 3) c = 0;
    }

    // ---- epilogue: C = acc + bias (C-frag: row=q4*4+r, col=lx per 16x16) ----
    #pragma unroll
    for (int nf = 0; nf < 2; ++nf) {
        const int col = n0 + wc * 32 + nf * 16 + lx;
        const float bv = bias[col];
        #pragma unroll
        for (int mf = 0; mf < 4; ++mf) {
            const int row0 = m0 + wr * 64 + mf * 16 + q4 * 4;
            #pragma unroll
            for (int r = 0; r < 4; ++r)
                C[(size_t)(row0 + r) * DIMSZ + col] = acc[mf][nf][r] + bv;
        }
    }
}

// ---------------------------------------------------------------------------
// MFMA GEMM (fallback path only, !xsplit): C = A*B^T, fp16 2-term, MODE 1
// QKV epilogue. 128x128 tile, BK=32, 256 thr = 4 waves, reg-staged split.
// ---------------------------------------------------------------------------
template <int MODE, bool ASPLIT>
__global__ __launch_bounds__(256, 3)
void mfma_gemm_abt(const float* __restrict__ A,
                   const unsigned short* __restrict__ AHg,
                   const unsigned short* __restrict__ ALg,
                   const unsigned short* __restrict__ BHg,
                   const float* __restrict__ bias, float* __restrict__ C,
                   unsigned short* __restrict__ QH, unsigned short* __restrict__ QL,
                   unsigned short* __restrict__ KH, unsigned short* __restrict__ VT,
                   int M, int N, int K)
{
    constexpr int LDP = ASPLIT ? 32 : 40;   // LDS row stride (ushorts)
    __shared__ unsigned short AHs[128 * LDP];
    __shared__ unsigned short ALs[128 * LDP];
    __shared__ unsigned short BHs[128 * LDP];

    const int t  = threadIdx.x;
    const int wv = t >> 6;
    const int ln = t & 63;
    const int lx = ln & 15;
    const int q4 = ln >> 4;
    const int m0 = blockIdx.y * 128;
    const int n0 = blockIdx.x * 128;

    f32x4 acc[2][8];
    #pragma unroll
    for (int mf = 0; mf < 2; ++mf)
        #pragma unroll
        for (int nf = 0; nf < 8; ++nf)
            acc[mf][nf] = (f32x4){0.f, 0.f, 0.f, 0.f};

    for (int k0 = 0; k0 < K; k0 += 32) {
        if constexpr (ASPLIT) {
            const int rowc = ln >> 2;            // row within chunk
            const int c8   = (ln & 3) << 3;      // ushort offset within row
            #pragma unroll
            for (int rep = 0; rep < 2; ++rep) {
                const int chunk = rep * 4 + wv;  // 0..7, wave-uniform
                const int r = chunk * 16 + rowc;
                const size_t goff = (size_t)(m0 + r) * K + k0 + c8;
                const size_t boff = (size_t)(n0 + r) * K + k0 + c8;
                async16(&AHs[chunk * 16 * LDP], AHg + goff);
                async16(&ALs[chunk * 16 * LDP], ALg + goff);
                async16(&BHs[chunk * 16 * LDP], BHg + boff);
            }
        } else {
            #pragma unroll
            for (int rep = 0; rep < 2; ++rep) {
                const int task = rep * 256 + t;          // 0..511
                const int r  = task >> 2;
                const int sg = (task & 3) << 3;          // element offset 0,8,16,24
                {
                    const float* p = A + (size_t)(m0 + r) * K + k0 + sg;
                    float4 f0 = *(const float4*)p;
                    float4 f1 = *(const float4*)(p + 4);
                    ushort8 h, l; split8h(f0, f1, h, l);
                    *(ushort8*)&AHs[r * LDP + sg] = h;
                    *(ushort8*)&ALs[r * LDP + sg] = l;
                }
                {
                    const size_t off = (size_t)(n0 + r) * K + k0 + sg;
                    *(ushort8*)&BHs[r * LDP + sg] = *(const ushort8*)(BHg + off);
                }
            }
        }
        __syncthreads();   // drains vmcnt (global_load_lds) + lgkmcnt

        short8 ah[2], al[2];
        #pragma unroll
        for (int mf = 0; mf < 2; ++mf) {
            const int row = wv * 32 + mf * 16 + lx;
            ah[mf] = *(const short8*)&AHs[row * LDP + q4 * 8];
            al[mf] = *(const short8*)&ALs[row * LDP + q4 * 8];
        }
        #pragma unroll
        for (int nf = 0; nf < 8; ++nf) {
            const short8 bh = *(const short8*)&BHs[(nf * 16 + lx) * LDP + q4 * 8];
            #pragma unroll
            for (int mf = 0; mf < 2; ++mf) {
                acc[mf][nf] = MFMA_F16(ah[mf], bh, acc[mf][nf]);
                acc[mf][nf] = MFMA_F16(al[mf], bh, acc[mf][nf]);
            }
        }
        __syncthreads();
    }

    // ---- epilogue (C-frag: row = q4*4+r, col = lx within each 16x16) ----
    if constexpr (MODE == 0) {
        #pragma unroll
        for (int nf = 0; nf < 8; ++nf) {
            const int col = n0 + nf * 16 + lx;
            const float bv = bias[col];
            #pragma unroll
            for (int mf = 0; mf < 2; ++mf) {
                const int row0 = m0 + wv * 32 + mf * 16 + q4 * 4;
                #pragma unroll
                for (int r = 0; r < 4; ++r)
                    C[(size_t)(row0 + r) * N + col] = acc[mf][nf][r] + bv;
            }
        }
    } else {
        const int part = n0 >> 10;                   // whole block in one part
        #pragma unroll
        for (int nf = 0; nf < 8; ++nf) {
            const int colb = n0 + nf * 16;
            const int head = (colb >> 6) & 15;
            const int d0   = (colb & 63) + lx;
            if (part == 0) {
                #pragma unroll
                for (int mf = 0; mf < 2; ++mf) {
                    const int row0 = m0 + wv * 32 + mf * 16 + q4 * 4;
                    #pragma unroll
                    for (int r = 0; r < 4; ++r) {
                        const float v = acc[mf][nf][r] * ATT_SCALE;
                        const unsigned short h = f2hu(v);
                        const size_t idx = ((size_t)head * SEQ + row0 + r) * HDIM + d0;
                        QH[idx] = h;
                        QL[idx] = f2hu(v - hu2f(h));
                    }
                }
            } else if (part == 1) {
                #pragma unroll
                for (int mf = 0; mf < 2; ++mf) {
                    const int row0 = m0 + wv * 32 + mf * 16 + q4 * 4;
                    #pragma unroll
                    for (int r = 0; r < 4; ++r) {
                        const size_t idx = ((size_t)head * SEQ + row0 + r) * HDIM + d0;
                        KH[idx] = f2hu(acc[mf][nf][r]);
                    }
                }
            } else {
                unsigned short* base = VT + ((size_t)head * HDIM + d0) * SEQ;
                #pragma unroll
                for (int mf = 0; mf < 2; ++mf) {
                    const int row0 = m0 + wv * 32 + mf * 16 + q4 * 4;
                    ushort4 o;
                    o.x = f2hu(acc[mf][nf][0]); o.y = f2hu(acc[mf][nf][1]);
                    o.z = f2hu(acc[mf][nf][2]); o.w = f2hu(acc[mf][nf][3]);
                    *(ushort4*)(base + row0) = o;
                }
            }
        }
    }
}

// ---------------------------------------------------------------------------
// Flash attention, fp16 MFMA, S^T formulation, register-resident P transit.
// R15: 128-query blocks, 8 waves (waves 0-3 = query group 0, 4-7 = group 1)
// sharing each staged K/V tile -> per-query K/V L3 traffic HALVED (1 GB ->
// 0.5 GB). Rationale: attn showed MfmaUtil ~25 / VALU ~26 / HBM ~6% with
// ~7.1 TB/s of L3 K/V reads -> L3-BW-bound. R3's version of this geometry
// failed on VGPR spill from reg-staging + launch_bounds cap; both causes
// are gone (gload_lds staging, no cap).
// Per-wave compute identical to the R6-proven kernel (wq = wv&3 owns keys;
// Q rows offset by wg*64). Staging: 4 async16/tile (512 lanes x 16B).
// LDS: KA[0,16K) VA[16K,32K) KB[32K,48K) VB[48K,64K);
//      epilogue obuf[8][32][68]=69632 (overlays staging) + lbuf 2048 -> 71680.
// ---------------------------------------------------------------------------
__global__ __launch_bounds__(512, 2)
void attn_mfma(const unsigned short* __restrict__ QHg,
               const unsigned short* __restrict__ QLg,
               const unsigned short* __restrict__ KHg,
               const unsigned short* __restrict__ VTg,
               unsigned short* __restrict__ AttnH,
               unsigned short* __restrict__ AttnL)
{
    __shared__ __align__(16) char shraw[71680];
    unsigned short* KA = (unsigned short*)shraw;                 // [128][64]
    unsigned short* VA = (unsigned short*)(shraw + 16384);       // [64][128]
    unsigned short* KB = (unsigned short*)(shraw + 32768);
    unsigned short* VB = (unsigned short*)(shraw + 49152);
    float* obuf = (float*)shraw;                                 // [8][32][68]
    float* lbuf = (float*)(shraw + 69632);                       // [2][4][64]

    const int t  = threadIdx.x;
    const int wv = t >> 6;
    const int wg = wv >> 2;               // query group 0/1
    const int wq = wv & 3;                // wave-within-group (key owner)
    const int ln = t & 63;
    const int q4 = ln >> 4;
    const int lx = ln & 15;
    const int qb   = blockIdx.x;          // 128-query block
    const int head = blockIdx.y;

    const unsigned short* Kh = KHg + (size_t)head * SEQ * HDIM;   // [n][64]
    const unsigned short* Vg = VTg + (size_t)head * HDIM * SEQ;   // [d][4096]

    // ---- Q B-frags (this wave's query group), registers for whole kernel ----
    short8 qh[4][2], ql[4][2];
    #pragma unroll
    for (int qt = 0; qt < 4; ++qt)
        #pragma unroll
        for (int s = 0; s < 2; ++s) {
            const size_t off = ((size_t)head * SEQ + (size_t)qb * 128 + wg * 64
                                + qt * 16 + lx) * HDIM + s * 32 + q4 * 8;
            qh[qt][s] = *(const short8*)(QHg + off);
            ql[qt][s] = *(const short8*)(QLg + off);
        }

    f32x4 o_acc[4][4];   // [dt][qt]: O^T[d=dt*16+q4*4+r][q=qt*16+lx] (wave-partial)
    float l_part[4] = {0.f, 0.f, 0.f, 0.f};
    #pragma unroll
    for (int dt = 0; dt < 4; ++dt)
        #pragma unroll
        for (int qt = 0; qt < 4; ++qt)
            o_acc[dt][qt] = (f32x4){0.f, 0.f, 0.f, 0.f};

    // per-thread staging constants (pre-swizzled global sources, rule #21).
    // 512 lanes: K chunk = 64 rows (2 chunks), V chunk = 32 rows (2 chunks).
    const int rK8 = t >> 3;                       // K row within 64-row chunk
    const int gck = ((t & 7) ^ (rK8 & 7)) << 3;   // K global elem offset (swz)
    const int rV4 = t >> 4;                       // V row within 32-row chunk
    const int gcv = ((t & 15) ^ (rV4 & 7)) << 3;  // V global elem offset (swz)

    auto issue_tile = [&](int kbase, unsigned short* KX, unsigned short* VX) {
        #pragma unroll
        for (int c = 0; c < 2; ++c) {
            async16(KX + (c * 64) * 64 + (t >> 6) * 512,
                    Kh + (size_t)(kbase + c * 64 + rK8) * HDIM + gck);
            async16(VX + (c * 32) * 128 + (t >> 6) * 512,
                    Vg + (size_t)(c * 32 + rV4) * SEQ + kbase + gcv);
        }
    };

    auto compute_tile = [&](const unsigned short* KX, const unsigned short* VX) {
        // ---- S^T = K Q^T per sub-tile; exp packs straight into PV B-frags ----
        short8 phi[4];
        #pragma unroll
        for (int st = 0; st < 2; ++st) {
            const int kr = st * 64 + wq * 16 + lx;   // this lane's A-row (key)
            short8 kfh[2];
            #pragma unroll
            for (int s = 0; s < 2; ++s)
                kfh[s] = *(const short8*)&KX[kr * 64 + (((s * 4 + q4) ^ (kr & 7)) << 3)];
            #pragma unroll
            for (int qt = 0; qt < 4; ++qt) {
                f32x4 sa = (f32x4){0.f, 0.f, 0.f, 0.f};
                __builtin_amdgcn_s_setprio(1);
                #pragma unroll
                for (int s = 0; s < 2; ++s) {
                    sa = MFMA_F16(kfh[s], qh[qt][s], sa);
                    sa = MFMA_F16(kfh[s], ql[qt][s], sa);
                }
                __builtin_amdgcn_s_setprio(0);
                #pragma unroll
                for (int r = 0; r < 4; ++r) {
                    const float e = __expf(sa[r]);
                    l_part[qt] += e;
                    phi[qt][st * 4 + r] = (short)f2hu(e);
                }
            }
        }
        // ---- O^T += V^T P^T (A=V^T two b64 reads w/ matching permutation) ----
        const int colb = wq * 32 + q4 * 8;     // byte col of v0 within V row
        const int sl0  = colb >> 4;            // logical 16B slot (0..7)
        const int sub  = (colb & 15) >> 1;     // elem offset within slot (0 or 4)
        #pragma unroll
        for (int dt = 0; dt < 4; ++dt) {
            const int vr = dt * 16 + lx;
            const s16x4 v0 = *(const s16x4*)&VX[vr * 128 + (((sl0    ) ^ (vr & 7)) << 3) + sub];
            const s16x4 v1 = *(const s16x4*)&VX[vr * 128 + (((sl0 + 8) ^ (vr & 7)) << 3) + sub];
            short8 vf;
            #pragma unroll
            for (int i = 0; i < 4; ++i) { vf[i] = v0[i]; vf[i + 4] = v1[i]; }
            __builtin_amdgcn_s_setprio(1);
            #pragma unroll
            for (int qt = 0; qt < 4; ++qt)
                o_acc[dt][qt] = MFMA_F16(vf, phi[qt], o_acc[dt][qt]);
            __builtin_amdgcn_s_setprio(0);
        }
    };

    // prologue: tile 0 -> buf A (syncthreads drains vmcnt)
    issue_tile(0, KA, VA);
    __syncthreads();

    // main loop: 32 tiles, pair-unrolled for static buffer selection.
    for (int i = 0; i < SEQ / 256; ++i) {
        const int mt = 2 * i;
        if (mt + 1 < SEQ / 128) issue_tile((mt + 1) * 128, KB, VB);
        compute_tile(KA, VA);
        __syncthreads();                       // drains B's DMA; closes A reads
        if (mt + 2 < SEQ / 128) issue_tile((mt + 2) * 128, KA, VA);
        compute_tile(KB, VB);
        __syncthreads();                       // drains A's DMA; closes B reads
    }

    // ---- epilogue: reduce l and O^T across the 4 waves of each group ----
    float lw[4];
    #pragma unroll
    for (int qt = 0; qt < 4; ++qt) {
        float l = l_part[qt];
        l += __shfl_xor(l, 16);
        l += __shfl_xor(l, 32);
        lw[qt] = l;                                  // wave-total for q=qt*16+lx
    }
    if (q4 == 0) {
        #pragma unroll
        for (int qt = 0; qt < 4; ++qt)
            lbuf[wg * 256 + wq * 64 + qt * 16 + lx] = lw[qt];
    }
    #pragma unroll
    for (int p = 0; p < 2; ++p) {
        #pragma unroll
        for (int dd = 0; dd < 2; ++dd) {
            const int dt = p * 2 + dd;
            #pragma unroll
            for (int qt = 0; qt < 4; ++qt)
                #pragma unroll
                for (int r = 0; r < 4; ++r)
                    obuf[wv * 2176 + (dd * 16 + q4 * 4 + r) * 68 + qt * 16 + lx]
                        = o_acc[dt][qt][r];
        }
        __syncthreads();
        {
            const int q2 = t >> 2;                   // 0..127 (block-local query)
            const int g  = q2 >> 6, q = q2 & 63;
            const int dg = (t & 3) << 3;
            const float linv = 1.f / (lbuf[g * 256 + q] + lbuf[g * 256 + 64 + q]
                                    + lbuf[g * 256 + 128 + q] + lbuf[g * 256 + 192 + q]);
            const float* ob0 = obuf + (size_t)(g * 4) * 2176;
            ushort8 ho, lo;
            #pragma unroll
            for (int j = 0; j < 8; ++j) {
                const int dloc = dg + j;
                const float s = ob0[dloc * 68 + q] + ob0[2176 + dloc * 68 + q]
                              + ob0[4352 + dloc * 68 + q] + ob0[6528 + dloc * 68 + q];
                const float v = s * linv;
                const unsigned short h = f2hu(v);
                ho[j] = (short)h;
                lo[j] = (short)f2hu(v - hu2f(h));
            }
            const size_t ob = (size_t)(qb * 128 + q2) * DIMSZ + head * HDIM + p * 32 + dg;
            *(ushort8*)(AttnH + ob) = ho;
            *(ushort8*)(AttnL + ob) = lo;
        }
        __syncthreads();
    }
}

// ---------------------------------------------------------------------------
extern "C" void kernel_launch(void* const* d_in, const int* in_sizes, int n_in,
                              void* d_out, int out_size, void* d_ws,
                              size_t ws_size, hipStream_t stream)
{
    const float* x     = (const float*)d_in[0];   // [4096, 3072]
    const float* Wqkv  = (const float*)d_in[1];   // [3072, 3072]
    const float* Wproj = (const float*)d_in[2];   // [1024, 1024]
    const float* bproj = (const float*)d_in[3];   // [1024]
    float* out = (float*)d_out;

    const size_t NWQ = (size_t)3072 * 3072;       // 9437184
    const size_t NWP = (size_t)1024 * 1024;       // 1048576
    const size_t NX  = (size_t)4096 * 3072;       // 12582912

    unsigned short* ub = (unsigned short*)d_ws;
    unsigned short* AttnH = ub;                   // [4096][1024]
    unsigned short* AttnL = ub + QSZ;
    unsigned short* QHg = ub + 2 * QSZ;           // [16][4096][64]
    unsigned short* QLg = ub + 3 * QSZ;
    unsigned short* KHg = ub + 4 * QSZ;
    unsigned short* VTg = ub + 5 * QSZ;           // [16][64][4096]
    unsigned short* WQH = ub + 6 * QSZ;           // [3072][3072] hi
    unsigned short* WPH = WQH + NWQ;              // [1024][1024] hi
    unsigned short* XH  = WPH + NWP;              // [4096][3072] hi
    unsigned short* XL  = XH + NX;                // [4096][3072] lo
    const bool xsplit = ws_size >= 121634816ull;

    // 0) prep: split x (hi/lo) if room; cast W_qkv/W_proj to fp16 hi.
    prep_split<<<2048, 256, 0, stream>>>(
        xsplit ? x : nullptr, XH, XL, xsplit ? (int)NX : 0,
        Wqkv, WQH, (int)NWQ, Wproj, WPH, (int)NWP);

    // 1) qkv = x @ Wqkv^T (fp16 2-term) -> pre-converted attention operands
    if (xsplit) {
        qkv_gemm_8ph<<<256, 512, 0, stream>>>(
            XH, XL, WQH, QHg, QLg, KHg, VTg);
    } else {
        dim3 g1(3 * DIMSZ / 128, SEQ / 128);   // 24 x 32
        mfma_gemm_abt<1, false><<<g1, 256, 0, stream>>>(
            x, nullptr, nullptr, WQH, nullptr, nullptr,
            QHg, QLg, KHg, VTg, SEQ, 3 * DIMSZ, 3 * DIMSZ);
    }

    // 2) attention: 128-query blocks, 8 waves (2 query groups share K/V tile)
    dim3 g2(SEQ / 128, NHEADS);            // 32 x 16
    attn_mfma<<<g2, 512, 0, stream>>>(QHg, QLg, KHg, VTg, AttnH, AttnL);

    // 3) out = attn @ Wproj^T + bproj (fp16 2-term, ring-3 schedule)
    proj_gemm_r3<<<256, 512, 0, stream>>>(AttnH, AttnL, WPH, bproj, out);
}